// Round 1
// baseline (147.082 us; speedup 1.0000x reference)
//
#include <hip/hip_runtime.h>
#include <math.h>

// Problem: N=65536 rows, D=256 fp32. out = sum_i (counts_i - 1)*d_i + exp(d_i)
// where d_i = dot(z_a[i], z_b[i]), counts_i = n-2 (i < n-1), n-1 (i == n-1).
// Memory-bound: 128 MiB read -> ~20 us floor at 6.3 TB/s achievable.

#define D_DIM 256
#define MAIN_BLOCKS 2048   // 8 blocks/CU on 256 CUs
#define WAVES_PER_BLOCK 4

__global__ __launch_bounds__(256)
void dot_loss_partial(const float* __restrict__ za,
                      const float* __restrict__ zb,
                      float* __restrict__ partial,
                      int n) {
    const int lane = threadIdx.x & 63;
    const int wave = threadIdx.x >> 6;
    const int rowStart = blockIdx.x * WAVES_PER_BLOCK + wave;
    const int rowStride = gridDim.x * WAVES_PER_BLOCK;

    float acc = 0.0f;

    for (int row = rowStart; row < n; row += rowStride) {
        // 64 lanes x float4 = 256 floats = one full row, perfectly coalesced.
        const float4* a4 = (const float4*)(za + (size_t)row * D_DIM);
        const float4* b4 = (const float4*)(zb + (size_t)row * D_DIM);
        float4 av = a4[lane];
        float4 bv = b4[lane];
        float d = av.x * bv.x;
        d = fmaf(av.y, bv.y, d);
        d = fmaf(av.z, bv.z, d);
        d = fmaf(av.w, bv.w, d);
        // wave-64 reduction
        #pragma unroll
        for (int off = 32; off > 0; off >>= 1)
            d += __shfl_down(d, off);
        if (lane == 0) {
            // (counts_i - 1): n-3 for i < n-1, n-2 for the last row
            float coeff = (row == n - 1) ? (float)(n - 2) : (float)(n - 3);
            acc = fmaf(coeff, d, acc) + expf(d) - 0.0f;
        }
    }

    __shared__ float smem[WAVES_PER_BLOCK];
    if (lane == 0) smem[wave] = acc;
    __syncthreads();
    if (threadIdx.x == 0) {
        float s = 0.0f;
        #pragma unroll
        for (int w = 0; w < WAVES_PER_BLOCK; ++w) s += smem[w];
        partial[blockIdx.x] = s;
    }
}

__global__ __launch_bounds__(256)
void reduce_partials(const float* __restrict__ partial,
                     float* __restrict__ out,
                     int m) {
    const int lane = threadIdx.x & 63;
    const int wave = threadIdx.x >> 6;
    double s = 0.0;
    for (int i = threadIdx.x; i < m; i += 256)
        s += (double)partial[i];
    #pragma unroll
    for (int off = 32; off > 0; off >>= 1)
        s += __shfl_down(s, off);
    __shared__ double smem[4];
    if (lane == 0) smem[wave] = s;
    __syncthreads();
    if (threadIdx.x == 0)
        out[0] = (float)(smem[0] + smem[1] + smem[2] + smem[3]);
}

extern "C" void kernel_launch(void* const* d_in, const int* in_sizes, int n_in,
                              void* d_out, int out_size, void* d_ws, size_t ws_size,
                              hipStream_t stream) {
    const float* za = (const float*)d_in[0];
    const float* zb = (const float*)d_in[1];
    float* out = (float*)d_out;
    float* partial = (float*)d_ws;  // MAIN_BLOCKS floats of scratch
    const int n = in_sizes[0] / D_DIM;

    dot_loss_partial<<<MAIN_BLOCKS, 256, 0, stream>>>(za, zb, partial, n);
    reduce_partials<<<1, 256, 0, stream>>>(partial, out, MAIN_BLOCKS);
}